// Round 1
// baseline (182.869 us; speedup 1.0000x reference)
//
#include <hip/hip_runtime.h>
#include <math.h>

#define EPSV 1e-10

__device__ __forceinline__ double dplus(double x) {
    // x*(x>EPS) + EPS*(x<EPS), EPS=1e-10
    return x > EPSV ? x : (x < EPSV ? EPSV : 0.0);
}

__device__ __forceinline__ int lower_bound_f(const float* __restrict__ arr, int n, float v) {
    int lo = 0, hi = n;
    while (lo < hi) {
        int mid = (lo + hi) >> 1;
        if (arr[mid] < v) lo = mid + 1; else hi = mid;
    }
    return lo;  // first index with arr[idx] >= v
}

// ---------------------------------------------------------------------------
// Kernel A: per-row banded sums a_[i], b_[i], c_[i]  (j <= i, incl. diagonal)
// a_ = sum c2*e,  b_ = sum (c1+2*c2*dt)*e,  c_ = sum (c0+c1*dt+c2*dt^2)*e
// where dt = min(t_i - t_j, 50), e = exp(-zeta*dt).
// Terms with dt > 50 (clamped) are ~exp(-50*zeta)*poly(50) — skipped when
// provably negligible (< 1e-13), else full-range fallback.
// ---------------------------------------------------------------------------
extern "C" __global__ void __launch_bounds__(64)
rowsums_kernel(const float* __restrict__ t, int n,
               const float* __restrict__ log_zeta_p,
               const float* __restrict__ c0_p, const float* __restrict__ c1_p,
               const float* __restrict__ c2_p,
               float* __restrict__ a_out, float* __restrict__ b_out,
               float* __restrict__ c_out)
{
    const int i = blockIdx.x;
    const float zeta = expf(log_zeta_p[0]);
    const float c0 = c0_p[0], c1 = c1_p[0], c2 = c2_p[0];
    const float ti = t[i];

    float W = 50.0f;
    if (expf(-50.0f * zeta) * (fabsf(c0) + 50.0f * fabsf(c1) + 2500.0f * fabsf(c2) + 1.0f) > 1e-13f)
        W = 3.0e38f;  // tail not negligible -> scan the whole row
    const int jlo = lower_bound_f(t, i + 1, ti - W);

    double sa = 0.0, sb = 0.0, sc = 0.0;
    for (int j = jlo + (int)threadIdx.x; j <= i; j += 64) {
        float dt = fminf(ti - t[j], 50.0f);
        float ex = expf(-zeta * dt);
        sa += (double)(c2 * ex);
        sb += (double)((c1 + 2.0f * c2 * dt) * ex);
        sc += (double)((c0 + dt * (c1 + dt * c2)) * ex);
    }
    for (int off = 32; off > 0; off >>= 1) {
        sa += __shfl_down(sa, off);
        sb += __shfl_down(sb, off);
        sc += __shfl_down(sc, off);
    }
    if (threadIdx.x == 0) {
        a_out[i] = (float)sa;
        b_out[i] = (float)sb;
        c_out[i] = (float)sc;
    }
}

// ---------------------------------------------------------------------------
// Kernel B: per-event quartic root (f64 internals; d1^2-4*d0^3 cancels badly
// in f32), term_1 contribution -log(plus(mu + lamb)), lamb = c_ - c0.
// Block-reduces and atomically accumulates term1 and sum(roots).
// ---------------------------------------------------------------------------
extern "C" __global__ void __launch_bounds__(256)
quartic_kernel(const float* __restrict__ t, int n,
               const float* __restrict__ log_mu_p,
               const float* __restrict__ c0_p,
               const float* __restrict__ a_in, const float* __restrict__ b_in,
               const float* __restrict__ c_in,
               float* __restrict__ roots_shifted, double* __restrict__ accum)
{
    const int i = blockIdx.x * 256 + (int)threadIdx.x;
    const double mu = exp((double)log_mu_p[0]);
    double neg_log = 0.0, root = 0.0;
    if (i < n) {
        const double a_ = (double)a_in[i];
        const double b_ = (double)b_in[i];
        const double c_ = (double)c_in[i];
        const double a = 0.5 * a_;
        const double b = -a_ + 0.5 * b_;
        const double c = a_ - b_ + 0.5 * c_;
        const double d = b_ - c_;
        const double e = c_ + mu;

        const double p  = (8.0 * a * c - 3.0 * b * b) / (8.0 * a * a);
        const double q  = (b * b * b - 4.0 * a * b * c + 8.0 * a * a * d) / (8.0 * a * a * a);
        const double d0 = c * c - 3.0 * b * d + 12.0 * a * e;
        const double d1 = 2.0 * c * c * c - 9.0 * b * c * d + 27.0 * b * b * e
                        + 27.0 * a * d * d - 72.0 * a * c * e;
        const double temp1 = d1 * d1 - 4.0 * d0 * d0 * d0;
        const double Q  = cbrt((sqrt(dplus(temp1)) + d1) * 0.5);
        const double temp2 = -(2.0 / 3.0) * p + (Q + d0 / Q) / (3.0 * a);
        const double S  = sqrt(dplus(temp2)) * 0.5;
        const double temp3 = -4.0 * S * S - 2.0 * p + q / S;
        const double x1 = -b / (4.0 * a) - S + sqrt(dplus(temp3)) * 0.5;
        root = (S > 0.001 && x1 > 0.0) ? x1 : 0.0;

        const double lamb = dplus(mu + (c_ - (double)c0_p[0]));
        neg_log = -log(lamb);
        roots_shifted[i] = (float)root + t[i];
    }
    // block reduce (4 waves)
    double v1 = neg_log, v2 = root;
    for (int off = 32; off > 0; off >>= 1) {
        v1 += __shfl_down(v1, off);
        v2 += __shfl_down(v2, off);
    }
    __shared__ double s1[4], s2[4];
    const int wave = (int)threadIdx.x >> 6;
    if ((threadIdx.x & 63) == 0) { s1[wave] = v1; s2[wave] = v2; }
    __syncthreads();
    if (threadIdx.x == 0) {
        atomicAdd(&accum[0], s1[0] + s1[1] + s1[2] + s1[3]);  // term_1
        atomicAdd(&accum[1], s2[0] + s2[1] + s2[2] + s2[3]);  // sum(roots)
    }
}

// ---------------------------------------------------------------------------
// Kernel C: term_3 raw sum. Row i in [0, n]:
//   s = neg_start[i] = (i<n ? t[i] : t_end),  e = roots_cat[i] = (i==0 ? 0 : root+t[i-1])
//   sum_j antideriv(relu(s - t_j)) - antideriv(relu(e - t_j))
// Exactly 0 for t_j >= max(s,e); negligible (<1e-28) for t_j < min(s,e)-70/zeta.
// ---------------------------------------------------------------------------
extern "C" __global__ void __launch_bounds__(64)
term3_kernel(const float* __restrict__ t, int n,
             const float* __restrict__ log_zeta_p,
             const float* __restrict__ c0_p, const float* __restrict__ c1_p,
             const float* __restrict__ c2_p,
             const float* __restrict__ roots_shifted,
             const int* __restrict__ t_end_p,
             double* __restrict__ accum)
{
    const int i = blockIdx.x;  // 0 .. n
    const float zeta = expf(log_zeta_p[0]);
    const float c0 = c0_p[0], c1 = c1_p[0], c2 = c2_p[0];
    const float s = (i < n) ? t[i] : (float)t_end_p[0];
    const float e = (i == 0) ? 0.0f : roots_shifted[i - 1];

    const float hi_v = fmaxf(s, e);
    const float lo_v = fminf(s, e) - 70.0f / zeta;
    const int jlo = lower_bound_f(t, n, lo_v);
    const int jhi = lower_bound_f(t, n, hi_v);

    const float konst = c1 * zeta;  // not needed separately; keep per-term form
    (void)konst;
    double acc = 0.0;
    for (int j = jlo + (int)threadIdx.x; j < jhi; j += 64) {
        const float tj = t[j];
        const float xs = fmaxf(s - tj, 0.0f);
        const float xe = fmaxf(e - tj, 0.0f);
        const float zxs = zeta * xs;
        const float vs = expf(-zxs) *
            (-c2 * (zxs * (zxs + 2.0f) + 2.0f) - zeta * (c1 * zxs + c1 + c0 * zeta));
        const float zxe = zeta * xe;
        const float ve = expf(-zxe) *
            (-c2 * (zxe * (zxe + 2.0f) + 2.0f) - zeta * (c1 * zxe + c1 + c0 * zeta));
        acc += (double)(vs - ve);
    }
    for (int off = 32; off > 0; off >>= 1) acc += __shfl_down(acc, off);
    if (threadIdx.x == 0) atomicAdd(&accum[2], acc);
}

// ---------------------------------------------------------------------------
// Kernel D: combine terms.
// ---------------------------------------------------------------------------
extern "C" __global__ void finalize_kernel(const float* __restrict__ log_mu_p,
                                           const float* __restrict__ log_zeta_p,
                                           const int* __restrict__ t_start_p,
                                           const int* __restrict__ t_end_p,
                                           const double* __restrict__ accum,
                                           float* __restrict__ out)
{
    const double mu = exp((double)log_mu_p[0]);
    const double zeta = exp((double)log_zeta_p[0]);
    const double term1 = accum[0];
    const double term2 = mu * (double)(t_end_p[0] - t_start_p[0]) - accum[1] * mu;
    const double term3 = accum[2] / (zeta * zeta * zeta);
    out[0] = (float)(term1 + term2 + term3);
}

extern "C" void kernel_launch(void* const* d_in, const int* in_sizes, int n_in,
                              void* d_out, int out_size, void* d_ws, size_t ws_size,
                              hipStream_t stream)
{
    (void)n_in; (void)out_size; (void)ws_size;
    const float* his_t    = (const float*)d_in[0];
    const float* log_mu   = (const float*)d_in[1];
    const float* log_zeta = (const float*)d_in[2];
    const float* c0       = (const float*)d_in[3];
    const float* c1       = (const float*)d_in[4];
    const float* c2       = (const float*)d_in[5];
    const int*   t_start  = (const int*)d_in[6];
    const int*   t_end    = (const int*)d_in[7];
    const int n = in_sizes[0];

    // workspace layout: 4 float arrays of n, then 3 doubles (16n bytes is 8-aligned)
    float* a_  = (float*)d_ws;
    float* b_  = a_ + n;
    float* c_  = b_ + n;
    float* roots_shifted = c_ + n;
    double* accum = (double*)((char*)d_ws + (size_t)16 * (size_t)n);

    hipMemsetAsync(accum, 0, 3 * sizeof(double), stream);
    rowsums_kernel<<<n, 64, 0, stream>>>(his_t, n, log_zeta, c0, c1, c2, a_, b_, c_);
    quartic_kernel<<<(n + 255) / 256, 256, 0, stream>>>(his_t, n, log_mu, c0,
                                                        a_, b_, c_, roots_shifted, accum);
    term3_kernel<<<n + 1, 64, 0, stream>>>(his_t, n, log_zeta, c0, c1, c2,
                                           roots_shifted, t_end, accum);
    finalize_kernel<<<1, 1, 0, stream>>>(log_mu, log_zeta, t_start, t_end, accum,
                                         (float*)d_out);
}

// Round 3
// 103.827 us; speedup vs baseline: 1.7613x; 1.7613x over previous
//
#include <hip/hip_runtime.h>
#include <math.h>

#define EPSV 1e-10

__device__ __forceinline__ double dplus(double x) {
    // x*(x>EPS) + EPS*(x<EPS), EPS=1e-10
    return x > EPSV ? x : (x < EPSV ? EPSV : 0.0);
}

__device__ __forceinline__ int lower_bound_f(const float* __restrict__ arr, int n, float v) {
    int lo = 0, hi = n;
    while (lo < hi) {
        int mid = (lo + hi) >> 1;
        if (arr[mid] < v) lo = mid + 1; else hi = mid;
    }
    return lo;  // first index with arr[idx] >= v
}

// ---------------------------------------------------------------------------
// Kernel 1 (fused): per-row banded sums a_,b_,c_ (j <= i, incl. diagonal),
// then lane 0 solves the quartic in f64 and emits:
//   roots_shifted[i] = root + t[i]
//   p_neglog[i]      = -log(plus(mu + (c_ - c0)))     (term_1 contribution)
//   p_root[i]        = root                            (for term_2)
// Banded window: terms with dt > 50 are clamped; their weight is
// exp(-50*zeta)*poly(50) — skipped when provably < 1e-13, else full scan.
// ---------------------------------------------------------------------------
extern "C" __global__ void __launch_bounds__(64)
row_quartic_kernel(const float* __restrict__ t, int n,
                   const float* __restrict__ log_mu_p,
                   const float* __restrict__ log_zeta_p,
                   const float* __restrict__ c0_p, const float* __restrict__ c1_p,
                   const float* __restrict__ c2_p,
                   float* __restrict__ roots_shifted,
                   double* __restrict__ p_neglog, double* __restrict__ p_root)
{
    const int i = blockIdx.x;
    const float zeta = expf(log_zeta_p[0]);
    const float c0 = c0_p[0], c1 = c1_p[0], c2 = c2_p[0];
    const float ti = t[i];

    float W = 50.0f;
    if (expf(-50.0f * zeta) * (fabsf(c0) + 50.0f * fabsf(c1) + 2500.0f * fabsf(c2) + 1.0f) > 1e-13f)
        W = 3.0e38f;  // tail not negligible -> scan the whole row
    const int jlo = lower_bound_f(t, i + 1, ti - W);

    double sa = 0.0, sb = 0.0, sc = 0.0;
    for (int j = jlo + (int)threadIdx.x; j <= i; j += 64) {
        float dt = fminf(ti - t[j], 50.0f);
        float ex = expf(-zeta * dt);
        sa += (double)(c2 * ex);
        sb += (double)((c1 + 2.0f * c2 * dt) * ex);
        sc += (double)((c0 + dt * (c1 + dt * c2)) * ex);
    }
    for (int off = 32; off > 0; off >>= 1) {
        sa += __shfl_down(sa, off);
        sb += __shfl_down(sb, off);
        sc += __shfl_down(sc, off);
    }

    if (threadIdx.x == 0) {
        // Cast through float to match the round-1 (verified absmax=0) version,
        // which stored row sums as f32 before the f64 quartic.
        const double a_ = (double)(float)sa;
        const double b_ = (double)(float)sb;
        const double c_ = (double)(float)sc;
        const double mu = exp((double)log_mu_p[0]);

        const double a = 0.5 * a_;
        const double b = -a_ + 0.5 * b_;
        const double c = a_ - b_ + 0.5 * c_;
        const double d = b_ - c_;
        const double e = c_ + mu;

        const double p  = (8.0 * a * c - 3.0 * b * b) / (8.0 * a * a);
        const double q  = (b * b * b - 4.0 * a * b * c + 8.0 * a * a * d) / (8.0 * a * a * a);
        const double d0 = c * c - 3.0 * b * d + 12.0 * a * e;
        const double d1 = 2.0 * c * c * c - 9.0 * b * c * d + 27.0 * b * b * e
                        + 27.0 * a * d * d - 72.0 * a * c * e;
        const double temp1 = d1 * d1 - 4.0 * d0 * d0 * d0;
        const double Q  = cbrt((sqrt(dplus(temp1)) + d1) * 0.5);
        const double temp2 = -(2.0 / 3.0) * p + (Q + d0 / Q) / (3.0 * a);
        const double S  = sqrt(dplus(temp2)) * 0.5;
        const double temp3 = -4.0 * S * S - 2.0 * p + q / S;
        const double x1 = -b / (4.0 * a) - S + sqrt(dplus(temp3)) * 0.5;
        const double root = (S > 0.001 && x1 > 0.0) ? x1 : 0.0;

        const double lamb = dplus(mu + (c_ - (double)c0_p[0]));
        p_neglog[i] = -log(lamb);
        p_root[i] = root;
        roots_shifted[i] = (float)root + ti;
    }
}

// ---------------------------------------------------------------------------
// Kernel 2: term_3 raw-sum partial per row i in [0, n]:
//   s = (i<n ? t[i] : t_end),  e = (i==0 ? 0 : root+t[i-1])
//   p3[i] = sum_j antideriv(relu(s - t_j)) - antideriv(relu(e - t_j))
// Exactly 0 for t_j >= max(s,e); negligible (<1e-28) for t_j < min(s,e)-70/zeta.
// No atomics: one workspace slot per row.
// ---------------------------------------------------------------------------
extern "C" __global__ void __launch_bounds__(64)
term3_kernel(const float* __restrict__ t, int n,
             const float* __restrict__ log_zeta_p,
             const float* __restrict__ c0_p, const float* __restrict__ c1_p,
             const float* __restrict__ c2_p,
             const float* __restrict__ roots_shifted,
             const int* __restrict__ t_end_p,
             double* __restrict__ p3)
{
    const int i = blockIdx.x;  // 0 .. n
    const float zeta = expf(log_zeta_p[0]);
    const float c0 = c0_p[0], c1 = c1_p[0], c2 = c2_p[0];
    const float s = (i < n) ? t[i] : (float)t_end_p[0];
    const float e = (i == 0) ? 0.0f : roots_shifted[i - 1];

    const float hi_v = fmaxf(s, e);
    const float lo_v = fminf(s, e) - 70.0f / zeta;
    const int jlo = lower_bound_f(t, n, lo_v);
    const int jhi = lower_bound_f(t, n, hi_v);

    double acc = 0.0;
    for (int j = jlo + (int)threadIdx.x; j < jhi; j += 64) {
        const float tj = t[j];
        const float xs = fmaxf(s - tj, 0.0f);
        const float xe = fmaxf(e - tj, 0.0f);
        const float zxs = zeta * xs;
        const float vs = expf(-zxs) *
            (-c2 * (zxs * (zxs + 2.0f) + 2.0f) - zeta * (c1 * zxs + c1 + c0 * zeta));
        const float zxe = zeta * xe;
        const float ve = expf(-zxe) *
            (-c2 * (zxe * (zxe + 2.0f) + 2.0f) - zeta * (c1 * zxe + c1 + c0 * zeta));
        acc += (double)(vs - ve);
    }
    for (int off = 32; off > 0; off >>= 1) acc += __shfl_down(acc, off);
    if (threadIdx.x == 0) p3[i] = acc;
}

// ---------------------------------------------------------------------------
// Kernel 3: single-block reduction of all partials + final combine.
// Reads p_neglog[n], p_root[n], p3[n+1] (~192 KB of f64) — a few µs.
// ---------------------------------------------------------------------------
extern "C" __global__ void __launch_bounds__(256)
reduce_kernel(int n,
              const double* __restrict__ p_neglog,
              const double* __restrict__ p_root,
              const double* __restrict__ p3,
              const float* __restrict__ log_mu_p,
              const float* __restrict__ log_zeta_p,
              const int* __restrict__ t_start_p,
              const int* __restrict__ t_end_p,
              float* __restrict__ out)
{
    double s1 = 0.0, s2 = 0.0, s3 = 0.0;
    for (int i = (int)threadIdx.x; i < n; i += 256) {
        s1 += p_neglog[i];
        s2 += p_root[i];
    }
    for (int i = (int)threadIdx.x; i < n + 1; i += 256) s3 += p3[i];

    for (int off = 32; off > 0; off >>= 1) {
        s1 += __shfl_down(s1, off);
        s2 += __shfl_down(s2, off);
        s3 += __shfl_down(s3, off);
    }
    __shared__ double l1[4], l2[4], l3[4];
    const int wave = (int)threadIdx.x >> 6;
    if ((threadIdx.x & 63) == 0) { l1[wave] = s1; l2[wave] = s2; l3[wave] = s3; }
    __syncthreads();
    if (threadIdx.x == 0) {
        const double term1 = l1[0] + l1[1] + l1[2] + l1[3];
        const double sroot = l2[0] + l2[1] + l2[2] + l2[3];
        const double raw3  = l3[0] + l3[1] + l3[2] + l3[3];
        const double mu = exp((double)log_mu_p[0]);
        const double zeta = exp((double)log_zeta_p[0]);
        const double term2 = mu * (double)(t_end_p[0] - t_start_p[0]) - sroot * mu;
        const double term3 = raw3 / (zeta * zeta * zeta);
        out[0] = (float)(term1 + term2 + term3);
    }
}

extern "C" void kernel_launch(void* const* d_in, const int* in_sizes, int n_in,
                              void* d_out, int out_size, void* d_ws, size_t ws_size,
                              hipStream_t stream)
{
    (void)n_in; (void)out_size; (void)ws_size;
    const float* his_t    = (const float*)d_in[0];
    const float* log_mu   = (const float*)d_in[1];
    const float* log_zeta = (const float*)d_in[2];
    const float* c0       = (const float*)d_in[3];
    const float* c1       = (const float*)d_in[4];
    const float* c2       = (const float*)d_in[5];
    const int*   t_start  = (const int*)d_in[6];
    const int*   t_end    = (const int*)d_in[7];
    const int n = in_sizes[0];

    // workspace layout (all 8-aligned): p_neglog[n], p_root[n], p3[n+1], roots_shifted[n]
    double* p_neglog = (double*)d_ws;
    double* p_root   = p_neglog + n;
    double* p3       = p_root + n;
    float*  roots_shifted = (float*)(p3 + (n + 1));

    row_quartic_kernel<<<n, 64, 0, stream>>>(his_t, n, log_mu, log_zeta, c0, c1, c2,
                                             roots_shifted, p_neglog, p_root);
    term3_kernel<<<n + 1, 64, 0, stream>>>(his_t, n, log_zeta, c0, c1, c2,
                                           roots_shifted, t_end, p3);
    reduce_kernel<<<1, 256, 0, stream>>>(n, p_neglog, p_root, p3,
                                         log_mu, log_zeta, t_start, t_end,
                                         (float*)d_out);
}

// Round 4
// 100.629 us; speedup vs baseline: 1.8173x; 1.0318x over previous
//
#include <hip/hip_runtime.h>
#include <math.h>

#define EPSV 1e-10

__device__ __forceinline__ double dplus(double x) {
    // x*(x>EPS) + EPS*(x<EPS), EPS=1e-10
    return x > EPSV ? x : (x < EPSV ? EPSV : 0.0);
}

__device__ __forceinline__ int lower_bound_f(const float* __restrict__ arr, int n, float v) {
    int lo = 0, hi = n;
    while (lo < hi) {
        int mid = (lo + hi) >> 1;
        if (arr[mid] < v) lo = mid + 1; else hi = mid;
    }
    return lo;  // first index with arr[idx] >= v
}

// ---------------------------------------------------------------------------
// Kernel 1: THREAD-per-row (rows are ~50 elements wide — a whole wave per row
// wasted 6x3 f64 shuffle steps on ~1 element/lane). Each thread:
//   - banded sums a_,b_,c_ over j in [jlo, i] (dt clamped at 50; tail terms
//     exp(-50*zeta)*poly provably < 1e-13 are skipped, else full scan)
//   - f64 quartic root + term_1 contribution
//   - writes roots_shifted[i]; block-reduces neglog/root partials.
// ---------------------------------------------------------------------------
extern "C" __global__ void __launch_bounds__(128)
row_quartic_kernel(const float* __restrict__ t, int n,
                   const float* __restrict__ log_mu_p,
                   const float* __restrict__ log_zeta_p,
                   const float* __restrict__ c0_p, const float* __restrict__ c1_p,
                   const float* __restrict__ c2_p,
                   float* __restrict__ roots_shifted,
                   double* __restrict__ pk_neglog, double* __restrict__ pk_root)
{
    const int i = blockIdx.x * 128 + (int)threadIdx.x;
    const float zeta = expf(log_zeta_p[0]);
    const float c0 = c0_p[0], c1 = c1_p[0], c2 = c2_p[0];

    double neglog = 0.0, root = 0.0;
    if (i < n) {
        const float ti = t[i];
        float W = 50.0f;
        if (expf(-50.0f * zeta) * (fabsf(c0) + 50.0f * fabsf(c1) + 2500.0f * fabsf(c2) + 1.0f) > 1e-13f)
            W = 3.0e38f;  // tail not negligible -> scan the whole row
        const int jlo = lower_bound_f(t, i + 1, ti - W);

        double sa = 0.0, sb = 0.0, sc = 0.0;
        for (int j = jlo; j <= i; ++j) {
            const float dt = fminf(ti - t[j], 50.0f);
            const float ex = expf(-zeta * dt);
            sa += (double)(c2 * ex);
            sb += (double)((c1 + 2.0f * c2 * dt) * ex);
            sc += (double)((c0 + dt * (c1 + dt * c2)) * ex);
        }

        // Cast through float to match the verified (absmax=0) earlier version.
        const double a_ = (double)(float)sa;
        const double b_ = (double)(float)sb;
        const double c_ = (double)(float)sc;
        const double mu = exp((double)log_mu_p[0]);

        const double a = 0.5 * a_;
        const double b = -a_ + 0.5 * b_;
        const double c = a_ - b_ + 0.5 * c_;
        const double d = b_ - c_;
        const double e = c_ + mu;

        const double p  = (8.0 * a * c - 3.0 * b * b) / (8.0 * a * a);
        const double q  = (b * b * b - 4.0 * a * b * c + 8.0 * a * a * d) / (8.0 * a * a * a);
        const double d0 = c * c - 3.0 * b * d + 12.0 * a * e;
        const double d1 = 2.0 * c * c * c - 9.0 * b * c * d + 27.0 * b * b * e
                        + 27.0 * a * d * d - 72.0 * a * c * e;
        const double temp1 = d1 * d1 - 4.0 * d0 * d0 * d0;
        const double Q  = cbrt((sqrt(dplus(temp1)) + d1) * 0.5);
        const double temp2 = -(2.0 / 3.0) * p + (Q + d0 / Q) / (3.0 * a);
        const double S  = sqrt(dplus(temp2)) * 0.5;
        const double temp3 = -4.0 * S * S - 2.0 * p + q / S;
        const double x1 = -b / (4.0 * a) - S + sqrt(dplus(temp3)) * 0.5;
        root = (S > 0.001 && x1 > 0.0) ? x1 : 0.0;

        neglog = -log(dplus(mu + (c_ - (double)c0_p[0])));
        roots_shifted[i] = (float)root + ti;
    }

    // block reduce: 2 waves
    for (int off = 32; off > 0; off >>= 1) {
        neglog += __shfl_down(neglog, off);
        root   += __shfl_down(root, off);
    }
    __shared__ double l1[2], l2[2];
    const int wave = (int)threadIdx.x >> 6;
    if ((threadIdx.x & 63) == 0) { l1[wave] = neglog; l2[wave] = root; }
    __syncthreads();
    if (threadIdx.x == 0) {
        pk_neglog[blockIdx.x] = l1[0] + l1[1];
        pk_root[blockIdx.x]   = l2[0] + l2[1];
    }
}

// ---------------------------------------------------------------------------
// Kernel 2: THREAD-per-row term_3 partial, row i in [0, n]:
//   s = (i<n ? t[i] : t_end),  e = (i==0 ? 0 : root+t[i-1])
//   sum_j antideriv(relu(s - t_j)) - antideriv(relu(e - t_j))
// Exactly 0 for t_j >= max(s,e); negligible (<1e-28) for t_j < min(s,e)-70/zeta.
// ---------------------------------------------------------------------------
extern "C" __global__ void __launch_bounds__(128)
term3_kernel(const float* __restrict__ t, int n,
             const float* __restrict__ log_zeta_p,
             const float* __restrict__ c0_p, const float* __restrict__ c1_p,
             const float* __restrict__ c2_p,
             const float* __restrict__ roots_shifted,
             const int* __restrict__ t_end_p,
             double* __restrict__ pk3)
{
    const int i = blockIdx.x * 128 + (int)threadIdx.x;  // 0 .. n
    const float zeta = expf(log_zeta_p[0]);
    const float c0 = c0_p[0], c1 = c1_p[0], c2 = c2_p[0];

    double acc = 0.0;
    if (i <= n) {
        const float s = (i < n) ? t[i] : (float)t_end_p[0];
        const float e = (i == 0) ? 0.0f : roots_shifted[i - 1];

        const float hi_v = fmaxf(s, e);
        const float lo_v = fminf(s, e) - 70.0f / zeta;
        const int jlo = lower_bound_f(t, n, lo_v);
        const int jhi = lower_bound_f(t, n, hi_v);

        for (int j = jlo; j < jhi; ++j) {
            const float tj = t[j];
            const float xs = fmaxf(s - tj, 0.0f);
            const float xe = fmaxf(e - tj, 0.0f);
            const float zxs = zeta * xs;
            const float vs = expf(-zxs) *
                (-c2 * (zxs * (zxs + 2.0f) + 2.0f) - zeta * (c1 * zxs + c1 + c0 * zeta));
            const float zxe = zeta * xe;
            const float ve = expf(-zxe) *
                (-c2 * (zxe * (zxe + 2.0f) + 2.0f) - zeta * (c1 * zxe + c1 + c0 * zeta));
            acc += (double)(vs - ve);
        }
    }

    for (int off = 32; off > 0; off >>= 1) acc += __shfl_down(acc, off);
    __shared__ double l3[2];
    const int wave = (int)threadIdx.x >> 6;
    if ((threadIdx.x & 63) == 0) l3[wave] = acc;
    __syncthreads();
    if (threadIdx.x == 0) pk3[blockIdx.x] = l3[0] + l3[1];
}

// ---------------------------------------------------------------------------
// Kernel 3: reduce the ~193 block partials + final combine. Deterministic
// (no atomics anywhere -> identical result every graph replay).
// ---------------------------------------------------------------------------
extern "C" __global__ void __launch_bounds__(64)
finalize_kernel(int nb1, int nb2,
                const double* __restrict__ pk_neglog,
                const double* __restrict__ pk_root,
                const double* __restrict__ pk3,
                const float* __restrict__ log_mu_p,
                const float* __restrict__ log_zeta_p,
                const int* __restrict__ t_start_p,
                const int* __restrict__ t_end_p,
                float* __restrict__ out)
{
    double s1 = 0.0, s2 = 0.0, s3 = 0.0;
    for (int i = (int)threadIdx.x; i < nb1; i += 64) {
        s1 += pk_neglog[i];
        s2 += pk_root[i];
    }
    for (int i = (int)threadIdx.x; i < nb2; i += 64) s3 += pk3[i];
    for (int off = 32; off > 0; off >>= 1) {
        s1 += __shfl_down(s1, off);
        s2 += __shfl_down(s2, off);
        s3 += __shfl_down(s3, off);
    }
    if (threadIdx.x == 0) {
        const double mu = exp((double)log_mu_p[0]);
        const double zeta = exp((double)log_zeta_p[0]);
        const double term1 = s1;
        const double term2 = mu * (double)(t_end_p[0] - t_start_p[0]) - s2 * mu;
        const double term3 = s3 / (zeta * zeta * zeta);
        out[0] = (float)(term1 + term2 + term3);
    }
}

extern "C" void kernel_launch(void* const* d_in, const int* in_sizes, int n_in,
                              void* d_out, int out_size, void* d_ws, size_t ws_size,
                              hipStream_t stream)
{
    (void)n_in; (void)out_size; (void)ws_size;
    const float* his_t    = (const float*)d_in[0];
    const float* log_mu   = (const float*)d_in[1];
    const float* log_zeta = (const float*)d_in[2];
    const float* c0       = (const float*)d_in[3];
    const float* c1       = (const float*)d_in[4];
    const float* c2       = (const float*)d_in[5];
    const int*   t_start  = (const int*)d_in[6];
    const int*   t_end    = (const int*)d_in[7];
    const int n = in_sizes[0];

    const int nb1 = (n + 127) / 128;       // blocks for rows 0..n-1
    const int nb2 = (n + 1 + 127) / 128;   // blocks for rows 0..n

    // workspace: doubles first (8-aligned), then roots_shifted floats
    double* pk_neglog = (double*)d_ws;
    double* pk_root   = pk_neglog + nb1;
    double* pk3       = pk_root + nb1;
    float*  roots_shifted = (float*)(pk3 + nb2);

    row_quartic_kernel<<<nb1, 128, 0, stream>>>(his_t, n, log_mu, log_zeta, c0, c1, c2,
                                                roots_shifted, pk_neglog, pk_root);
    term3_kernel<<<nb2, 128, 0, stream>>>(his_t, n, log_zeta, c0, c1, c2,
                                          roots_shifted, t_end, pk3);
    finalize_kernel<<<1, 64, 0, stream>>>(nb1, nb2, pk_neglog, pk_root, pk3,
                                          log_mu, log_zeta, t_start, t_end,
                                          (float*)d_out);
}

// Round 6
// 85.059 us; speedup vs baseline: 2.1499x; 1.1830x over previous
//
#include <hip/hip_runtime.h>
#include <math.h>

#define EPSV 1e-10

__device__ __forceinline__ double dplus(double x) {
    // x*(x>EPS) + EPS*(x<EPS), EPS=1e-10
    return x > EPSV ? x : (x < EPSV ? EPSV : 0.0);
}

__device__ __forceinline__ int lower_bound_f(const float* __restrict__ arr, int n, float v) {
    int lo = 0, hi = n;
    while (lo < hi) {
        int mid = (lo + hi) >> 1;
        if (arr[mid] < v) lo = mid + 1; else hi = mid;
    }
    return lo;  // first index with arr[idx] >= v
}

// ---------------------------------------------------------------------------
// Kernel 1: QUAD-per-row (4 lanes stride the ~50-wide window; 2-step xor
// reduce; quartic computed redundantly by all 4 lanes — quad-uniform, no
// divergence). 32 rows per 128-thread block -> 256 blocks (all CUs busy).
//   - banded sums a_,b_,c_ over j in [jlo, i] (dt clamped at 50; tail terms
//     exp(-50*zeta)*poly provably < 1e-13 are skipped, else full scan)
//   - f64 quartic root + term_1 contribution
//   - writes roots_shifted[i]; block-reduces neglog/root partials (no atomics).
// ---------------------------------------------------------------------------
extern "C" __global__ void __launch_bounds__(128)
row_quartic_kernel(const float* __restrict__ t, int n,
                   const float* __restrict__ log_mu_p,
                   const float* __restrict__ log_zeta_p,
                   const float* __restrict__ c0_p, const float* __restrict__ c1_p,
                   const float* __restrict__ c2_p,
                   float* __restrict__ roots_shifted,
                   double* __restrict__ pk_neglog, double* __restrict__ pk_root)
{
    const int l    = (int)threadIdx.x & 3;        // lane within quad
    const int quad = (int)threadIdx.x >> 2;       // 0..31 within block
    const int i    = blockIdx.x * 32 + quad;      // row
    const float zeta = expf(log_zeta_p[0]);
    const float c0 = c0_p[0], c1 = c1_p[0], c2 = c2_p[0];

    double neglog = 0.0, root = 0.0;
    if (i < n) {
        const float ti = t[i];
        float W = 50.0f;
        if (expf(-50.0f * zeta) * (fabsf(c0) + 50.0f * fabsf(c1) + 2500.0f * fabsf(c2) + 1.0f) > 1e-13f)
            W = 3.0e38f;  // tail not negligible -> scan the whole row
        const int jlo = lower_bound_f(t, i + 1, ti - W);

        double sa = 0.0, sb = 0.0, sc = 0.0;
        for (int j = jlo + l; j <= i; j += 4) {
            const float dt = fminf(ti - t[j], 50.0f);
            const float ex = expf(-zeta * dt);
            sa += (double)(c2 * ex);
            sb += (double)((c1 + 2.0f * c2 * dt) * ex);
            sc += (double)((c0 + dt * (c1 + dt * c2)) * ex);
        }
        // quad reduce: all 4 lanes end with the full sums
        sa += __shfl_xor(sa, 1); sb += __shfl_xor(sb, 1); sc += __shfl_xor(sc, 1);
        sa += __shfl_xor(sa, 2); sb += __shfl_xor(sb, 2); sc += __shfl_xor(sc, 2);

        // Cast through float to match the verified (absmax=0) earlier version.
        const double a_ = (double)(float)sa;
        const double b_ = (double)(float)sb;
        const double c_ = (double)(float)sc;
        const double mu = exp((double)log_mu_p[0]);

        const double a = 0.5 * a_;
        const double b = -a_ + 0.5 * b_;
        const double c = a_ - b_ + 0.5 * c_;
        const double d = b_ - c_;
        const double e = c_ + mu;

        const double p  = (8.0 * a * c - 3.0 * b * b) / (8.0 * a * a);
        const double q  = (b * b * b - 4.0 * a * b * c + 8.0 * a * a * d) / (8.0 * a * a * a);
        const double d0 = c * c - 3.0 * b * d + 12.0 * a * e;
        const double d1 = 2.0 * c * c * c - 9.0 * b * c * d + 27.0 * b * b * e
                        + 27.0 * a * d * d - 72.0 * a * c * e;
        const double temp1 = d1 * d1 - 4.0 * d0 * d0 * d0;
        const double Q  = cbrt((sqrt(dplus(temp1)) + d1) * 0.5);
        const double temp2 = -(2.0 / 3.0) * p + (Q + d0 / Q) / (3.0 * a);
        const double S  = sqrt(dplus(temp2)) * 0.5;
        const double temp3 = -4.0 * S * S - 2.0 * p + q / S;
        const double x1 = -b / (4.0 * a) - S + sqrt(dplus(temp3)) * 0.5;
        root = (S > 0.001 && x1 > 0.0) ? x1 : 0.0;

        neglog = -log(dplus(mu + (c_ - (double)c0_p[0])));
        if (l == 0) roots_shifted[i] = (float)root + ti;
        else { neglog = 0.0; root = 0.0; }  // one contribution per row
    }

    // wave + block (2-wave) reduce
    for (int off = 32; off > 0; off >>= 1) {
        neglog += __shfl_down(neglog, off);
        root   += __shfl_down(root, off);
    }
    __shared__ double l1[2], l2[2];
    const int w = (int)threadIdx.x >> 6;
    if (((int)threadIdx.x & 63) == 0) { l1[w] = neglog; l2[w] = root; }
    __syncthreads();
    if (threadIdx.x == 0) {
        pk_neglog[blockIdx.x] = l1[0] + l1[1];
        pk_root[blockIdx.x]   = l2[0] + l2[1];
    }
}

// ---------------------------------------------------------------------------
// Kernel 2: QUAD-per-row term_3 partial, row i in [0, n]:
//   s = (i<n ? t[i] : t_end),  e = (i==0 ? 0 : root+t[i-1])
//   sum_j antideriv(relu(s - t_j)) - antideriv(relu(e - t_j))
// Exactly 0 for t_j >= max(s,e); negligible (<1e-28) for t_j < min(s,e)-70/zeta.
// ---------------------------------------------------------------------------
extern "C" __global__ void __launch_bounds__(128)
term3_kernel(const float* __restrict__ t, int n,
             const float* __restrict__ log_zeta_p,
             const float* __restrict__ c0_p, const float* __restrict__ c1_p,
             const float* __restrict__ c2_p,
             const float* __restrict__ roots_shifted,
             const int* __restrict__ t_end_p,
             double* __restrict__ pk3)
{
    const int l    = (int)threadIdx.x & 3;
    const int quad = (int)threadIdx.x >> 2;
    const int i    = blockIdx.x * 32 + quad;   // 0 .. n
    const float zeta = expf(log_zeta_p[0]);
    const float c0 = c0_p[0], c1 = c1_p[0], c2 = c2_p[0];

    double acc = 0.0;
    if (i <= n) {
        const float s = (i < n) ? t[i] : (float)t_end_p[0];
        const float e = (i == 0) ? 0.0f : roots_shifted[i - 1];

        const float hi_v = fmaxf(s, e);
        const float lo_v = fminf(s, e) - 70.0f / zeta;
        const int jlo = lower_bound_f(t, n, lo_v);
        const int jhi = lower_bound_f(t, n, hi_v);

        for (int j = jlo + l; j < jhi; j += 4) {
            const float tj = t[j];
            const float xs = fmaxf(s - tj, 0.0f);
            const float xe = fmaxf(e - tj, 0.0f);
            const float zxs = zeta * xs;
            const float vs = expf(-zxs) *
                (-c2 * (zxs * (zxs + 2.0f) + 2.0f) - zeta * (c1 * zxs + c1 + c0 * zeta));
            const float zxe = zeta * xe;
            const float ve = expf(-zxe) *
                (-c2 * (zxe * (zxe + 2.0f) + 2.0f) - zeta * (c1 * zxe + c1 + c0 * zeta));
            acc += (double)(vs - ve);
        }
    }

    for (int off = 32; off > 0; off >>= 1) acc += __shfl_down(acc, off);
    __shared__ double l3[2];
    const int w = (int)threadIdx.x >> 6;
    if (((int)threadIdx.x & 63) == 0) l3[w] = acc;
    __syncthreads();
    if (threadIdx.x == 0) pk3[blockIdx.x] = l3[0] + l3[1];
}

// ---------------------------------------------------------------------------
// Kernel 3: reduce the block partials + final combine. Deterministic
// (no atomics anywhere -> identical result every graph replay).
// ---------------------------------------------------------------------------
extern "C" __global__ void __launch_bounds__(64)
finalize_kernel(int nb1, int nb2,
                const double* __restrict__ pk_neglog,
                const double* __restrict__ pk_root,
                const double* __restrict__ pk3,
                const float* __restrict__ log_mu_p,
                const float* __restrict__ log_zeta_p,
                const int* __restrict__ t_start_p,
                const int* __restrict__ t_end_p,
                float* __restrict__ out)
{
    double s1 = 0.0, s2 = 0.0, s3 = 0.0;
    for (int i = (int)threadIdx.x; i < nb1; i += 64) {
        s1 += pk_neglog[i];
        s2 += pk_root[i];
    }
    for (int i = (int)threadIdx.x; i < nb2; i += 64) s3 += pk3[i];
    for (int off = 32; off > 0; off >>= 1) {
        s1 += __shfl_down(s1, off);
        s2 += __shfl_down(s2, off);
        s3 += __shfl_down(s3, off);
    }
    if (threadIdx.x == 0) {
        const double mu = exp((double)log_mu_p[0]);
        const double zeta = exp((double)log_zeta_p[0]);
        const double term1 = s1;
        const double term2 = mu * (double)(t_end_p[0] - t_start_p[0]) - s2 * mu;
        const double term3 = s3 / (zeta * zeta * zeta);
        out[0] = (float)(term1 + term2 + term3);
    }
}

extern "C" void kernel_launch(void* const* d_in, const int* in_sizes, int n_in,
                              void* d_out, int out_size, void* d_ws, size_t ws_size,
                              hipStream_t stream)
{
    (void)n_in; (void)out_size; (void)ws_size;
    const float* his_t    = (const float*)d_in[0];
    const float* log_mu   = (const float*)d_in[1];
    const float* log_zeta = (const float*)d_in[2];
    const float* c0       = (const float*)d_in[3];
    const float* c1       = (const float*)d_in[4];
    const float* c2       = (const float*)d_in[5];
    const int*   t_start  = (const int*)d_in[6];
    const int*   t_end    = (const int*)d_in[7];
    const int n = in_sizes[0];

    const int nb1 = (n + 31) / 32;       // 32 rows per block (quad-per-row)
    const int nb2 = (n + 1 + 31) / 32;

    // workspace: doubles first (8-aligned), then roots_shifted floats
    double* pk_neglog = (double*)d_ws;
    double* pk_root   = pk_neglog + nb1;
    double* pk3       = pk_root + nb1;
    float*  roots_shifted = (float*)(pk3 + nb2);

    row_quartic_kernel<<<nb1, 128, 0, stream>>>(his_t, n, log_mu, log_zeta, c0, c1, c2,
                                                roots_shifted, pk_neglog, pk_root);
    term3_kernel<<<nb2, 128, 0, stream>>>(his_t, n, log_zeta, c0, c1, c2,
                                          roots_shifted, t_end, pk3);
    finalize_kernel<<<1, 64, 0, stream>>>(nb1, nb2, pk_neglog, pk_root, pk3,
                                          log_mu, log_zeta, t_start, t_end,
                                          (float*)d_out);
}